// Round 15
// baseline (52.701 us; speedup 1.0000x reference)
//
#include <hip/hip_runtime.h>

#define DEV __device__ __forceinline__

typedef __fp16 h8 __attribute__((ext_vector_type(8)));
typedef __fp16 f2 __attribute__((ext_vector_type(2)));
typedef float f32x4 __attribute__((ext_vector_type(4)));
union U4H { uint4 u; h8 h; };
union HS { _Float16 h; unsigned short s; };

DEV unsigned h16(float x) { HS z; z.h = (_Float16)x; return (unsigned)z.s; }
DEV unsigned f2bits(f2 h) { union { f2 h; unsigned u; } x; x.h = h; return x.u; }
DEV float silu_f(float v) { return v / (1.0f + __expf(-v)); }

// bases plane: B0..B7 per cell (16B) at 0; sil plane at SIL_OFF (+64B skew:
// 8256/4 % 32 = 16 -> lane-half 3 decorrelated from halves 0-2).
// Plane capacity 512 cells (8 KB) each; layers are phase-split to fit.
#define SIL_OFF 8256

// Cox-de Boor (reference-exact) — used only in prep/tail (cheap paths).
DEV void bspline8(float x, float bb[8]) {
    float b[11];
#pragma unroll
    for (int i = 0; i < 11; ++i) {
        float g0 = (i - 3) * 0.4f - 1.0f;
        float g1 = (i - 2) * 0.4f - 1.0f;
        b[i] = ((x >= g0) && (x < g1)) ? 1.0f : 0.0f;
    }
#pragma unroll
    for (int d = 1; d <= 3; ++d) {
        const float inv = 1.0f / (0.4f * (float)d);
#pragma unroll
        for (int i = 0; i < 11 - d; ++i) {
            float gl = (i - 3) * 0.4f - 1.0f;
            float gr = (i - 3 + d + 1) * 0.4f - 1.0f;
            b[i] = (x - gl) * inv * b[i] + (gr - x) * inv * b[i + 1];
        }
    }
#pragma unroll
    for (int j = 0; j < 8; ++j) bb[j] = b[j];
}

DEV unsigned silpair(float sil) {
    unsigned sh = h16(sil);
    float shf = (float)(_Float16)sil;
    unsigned slo = h16(sil - shf);
    return sh | (slo << 16);
}

// ---------------------------------------------------------------------------
// Windowed expansion: CINP channels x NROWS cell-rows into the plane pair.
// Cell row r maps to image row y = row0 + r - 1 (border cells -> x=0 exp).
// Two conflict-free ds_write_b128 per cell; row-sil via __shfl_down sharing
// (mismatch only at cols WC-2/WC-1, never read since px <= W-1).
// ---------------------------------------------------------------------------
template <int CINP, int H, int W, int NROWS>
DEV void expand_win(const float* src, int row0, char* planes, int tid) {
    constexpr int WC = W + 2;
    constexpr int CELLS = CINP * NROWS * WC;
    const int ln = tid & 63;
    for (int cell = tid; cell < CELLS; cell += 256) {
        int c = cell / (NROWS * WC);
        int rr = cell - c * (NROWS * WC);
        int r = rr / WC, col = rr - r * WC;
        int y = row0 + r - 1, x = col - 1;
        bool yin = (unsigned)y < (unsigned)H;
        const float* srow = src + c * H * W + y * W;

        float v0 = (yin && (unsigned)x < (unsigned)W) ? srow[x] : 0.0f;

        // bases of THIS cell (closed-form cardinal cubic, funnel-shift place)
        float u = (v0 + 2.2f) * 2.5f;
        int mi = (int)u;
        bool valid = (u >= 0.0f) && (u < 11.0f);
        float t = u - (float)mi;
        float t2 = t * t, t3 = t2 * t;
        float omt = 1.0f - t;
        float p3 = omt * omt * omt * (1.0f / 6.0f);
        float p2 = (3.0f * t3 - 6.0f * t2 + 4.0f) * (1.0f / 6.0f);
        float p1 = (-3.0f * t3 + 3.0f * t2 + 3.0f * t + 1.0f) * (1.0f / 6.0f);
        float p0 = t3 * (1.0f / 6.0f);
        unsigned d0 = f2bits(__builtin_amdgcn_cvt_pkrtz(p3, p2));
        unsigned d1 = f2bits(__builtin_amdgcn_cvt_pkrtz(p1, p0));
        unsigned long long P = ((unsigned long long)d1 << 32) | d0;
        unsigned long long lo64 = 0ull, hi64 = 0ull;
        int shamt = (mi - 3) * 16;
        if (valid) {
            if (shamt < 0) {
                lo64 = P >> (-shamt);
            } else if (shamt < 64) {
                lo64 = P << shamt;
                hi64 = shamt ? (P >> (64 - shamt)) : 0ull;
            } else {
                hi64 = P << (shamt - 64);
            }
        }
        uint4 brec;
        brec.x = (unsigned)lo64;
        brec.y = (unsigned)(lo64 >> 32);
        brec.z = (unsigned)hi64;
        brec.w = (unsigned)(hi64 >> 32);
        *(uint4*)(planes + (size_t)cell * 16) = brec;  // store early: lower live range

        unsigned sp0 = silpair(silu_f(v0));
        unsigned sp1 = __shfl_down(sp0, 1);
        unsigned sp2 = __shfl_down(sp0, 2);
        if (ln >= 62) {
            float v1 = (yin && (unsigned)(x + 1) < (unsigned)W) ? srow[x + 1] : 0.0f;
            float v2 = (yin && (unsigned)(x + 2) < (unsigned)W) ? srow[x + 2] : 0.0f;
            sp1 = silpair(silu_f(v1));
            sp2 = silpair(silu_f(v2));
        }
        uint4 srec;
        srec.x = sp0;
        srec.y = sp1;
        srec.z = sp2;
        srec.w = 0u;
        *(uint4*)(planes + SIL_OFF + (size_t)cell * 16) = srec;
    }
}

// chunk rc = (local cin, dy): base cell offset (dx=0) in the planes.
template <int NROWS, int SC>
DEV constexpr int chunkcell(int rc) {
    return ((rc / 3) * NROWS + (rc % 3)) * SC;
}

// 2x2/2 maxpool of a 16x16 C-tile (rows = 2x8 positions, cols = channels)
template <int O, int PHV, int PWV>
DEV void poolwrite(f32x4 acc, int ty, int tx, int ln, float* s_next) {
    const int n = ln & 15, q = ln >> 4;
    float q0 = fmaxf(acc[0], acc[1]);
    float q1 = fmaxf(acc[2], acc[3]);
    float r0 = fmaxf(q0, __shfl_xor(q0, 32));
    float r1 = fmaxf(q1, __shfl_xor(q1, 32));
    if (ln < 32 && n < O && ty < PHV) {
        int ppx = tx * 4 + (q & 1) * 2;
        float* dst = s_next + n * (PHV * PWV) + ty * PWV + ppx;
        if (ppx < PWV) dst[0] = r0;
        if (ppx + 1 < PWV) dst[1] = r1;
    }
}

// ---------------------------------------------------------------------------
// L1 spatial-phase conv+pool: tiles for pool rows [ty_off, ty_off+TPW*4/TX),
// plane holds local rows 0..NROWS-1. Single B-set (KC chunks resident).
// ---------------------------------------------------------------------------
template <int H, int W, int O, int KC, int TX, int TPW, int PHV, int PWV,
          int NROWS>
DEV void conv_pool_l1(const uint4* __restrict__ pwB, const char* planes,
                      float* s_next, int tid, int ty_off) {
    constexpr int SC = W + 2;
    const int wv = tid >> 6, ln = tid & 63;
    const int m = ln & 15;
    const int half = ln >> 4;
    const int lane_off = (half == 3) ? SIL_OFF : half * 16;

    uint4 bw[KC];
#pragma unroll
    for (int i = 0; i < KC; ++i) bw[i] = pwB[i * 64 + ln];
#pragma unroll
    for (int tt = 0; tt < TPW; ++tt) {
        const int gid = wv * TPW + tt;
        const int tyl = gid / TX, tx = gid - tyl * TX;
        const int py = 2 * tyl + (m >> 3);  // local row, <= NROWS-3
        const int px = min(tx * 8 + (m & 7), W - 1);
        const int base = (py * SC + px) * 16 + lane_off;
        f32x4 acc = {0.f, 0.f, 0.f, 0.f};
#pragma unroll
        for (int i = 0; i < KC; ++i) {
            const int off = chunkcell<NROWS, SC>(i) * 16;
            U4H a; a.u = *(const uint4*)(planes + base + off);
            U4H b; b.u = bw[i];
            acc = __builtin_amdgcn_mfma_f32_16x16x32_f16(a.h, b.h, acc, 0, 0, 0);
        }
        poolwrite<O, PHV, PWV>(acc, ty_off + tyl, tx, ln, s_next);
    }
}

// ---------------------------------------------------------------------------
// Channel-phase accumulate-only conv: KCP chunks of this phase into acc[TPW].
// BWC kept small (3-4) to bound resident bw[] register pressure.
// ---------------------------------------------------------------------------
template <int H, int W, int KCP, int BWC, int TX, int TPW, int NROWS>
DEV void conv_accum(const uint4* __restrict__ pwB, const char* planes, int tid,
                    f32x4* acc) {
    constexpr int SC = W + 2;
    const int wv = tid >> 6, ln = tid & 63;
    const int m = ln & 15;
    const int half = ln >> 4;
    const int lane_off = (half == 3) ? SIL_OFF : half * 16;

    int base[TPW];
#pragma unroll
    for (int tt = 0; tt < TPW; ++tt) {
        const int gid = wv * TPW + tt;
        const int ty = gid / TX, tx = gid - ty * TX;
        const int py = min(2 * ty + (m >> 3), H - 1);
        const int px = min(tx * 8 + (m & 7), W - 1);
        base[tt] = (py * SC + px) * 16 + lane_off;
    }
#pragma unroll
    for (int kc = 0; kc < KCP; kc += BWC) {
        uint4 bw[BWC];
#pragma unroll
        for (int i = 0; i < BWC; ++i) bw[i] = pwB[(kc + i) * 64 + ln];
#pragma unroll
        for (int i = 0; i < BWC; ++i) {
            const int off = chunkcell<NROWS, SC>(kc + i) * 16;
#pragma unroll
            for (int tt = 0; tt < TPW; ++tt) {
                U4H a; a.u = *(const uint4*)(planes + base[tt] + off);
                U4H b; b.u = bw[i];
                acc[tt] = __builtin_amdgcn_mfma_f32_16x16x32_f16(a.h, b.h, acc[tt], 0, 0, 0);
            }
        }
    }
}

template <int O, int TX, int TPW, int PHV, int PWV>
DEV void pool_tiles(const f32x4* acc, int tid, float* s_next) {
    const int wv = tid >> 6, ln = tid & 63;
#pragma unroll
    for (int tt = 0; tt < TPW; ++tt) {
        const int gid = wv * TPW + tt;
        const int ty = gid / TX, tx = gid - ty * TX;
        poolwrite<O, PHV, PWV>(acc[tt], ty, tx, ln, s_next);
    }
}

// ---------------------------------------------------------------------------
// Prep: wr (collapsed layer-4 weights) + fragment-packed B for layers 1..3.
// K slot s within chunk (cin,dy): s<24 -> ws[tap(cin,dy,s/8), s%8];
// s in 24..29 -> f16(wb[tap(cin,dy,(s-24)/2)]); s=30,31 -> 0.
// d_ws f32 offsets: wr[0,4640); pwB1@4640 (768 u32); pwB2@5408 (3072);
// pwB3@8480 (6144).
// ---------------------------------------------------------------------------
DEV float wval(const float* wb, const float* ws, int NT, int O, int n, int k) {
    int chunk = k >> 5, s = k & 31;
    int cin = chunk / 3, dy = chunk - 3 * (chunk / 3);
    if (n >= O) return 0.f;
    if (s < 24) {
        int dx = s >> 3, j = s & 7;
        return ws[(n * NT + cin * 9 + dy * 3 + dx) * 8 + j];
    }
    if (s < 30) {
        int dx = (s - 24) >> 1;
        return (float)(_Float16)wb[n * NT + cin * 9 + dy * 3 + dx];
    }
    return 0.f;
}

DEV unsigned packw(float a, float b) { return h16(a) | (h16(b) << 16); }

__global__ __launch_bounds__(256) void kan_prep(
    const float* __restrict__ wb1, const float* __restrict__ ws1,
    const float* __restrict__ wb2, const float* __restrict__ ws2,
    const float* __restrict__ wb3, const float* __restrict__ ws3,
    const float* __restrict__ wb4, const float* __restrict__ ws4,
    float* __restrict__ wsbase) {
    float* wr = wsbase;
    const int bid = blockIdx.x;
    const int tid = threadIdx.x;

    if (bid == 0) {  // Wb~ [32][16]
        for (int i = tid; i < 512; i += 256) {
            int o = i / 16, c = i % 16;
            float s = 0.0f;
#pragma unroll
            for (int q = 0; q < 4; ++q) s += wb4[o * 64 + c * 4 + q];
            wr[i] = s;
        }
    } else if (bid == 1) {  // beta7[o] = 7 * sum_{f,j} ws4[o,f,j] * B_j(0)
        __shared__ float zb[8];
        if (tid == 0) {
            float zbb[8];
            bspline8(0.0f, zbb);
#pragma unroll
            for (int j = 0; j < 8; ++j) zb[j] = zbb[j];
        }
        __syncthreads();
        const int o = tid >> 3, j = tid & 7;
        float s = 0.0f;
        for (int f = 0; f < 64; ++f) s += ws4[(o * 64 + f) * 8 + j];
        s *= zb[j];
        s += __shfl_xor(s, 1);
        s += __shfl_xor(s, 2);
        s += __shfl_xor(s, 4);
        if (j == 0) wr[4608 + o] = 7.0f * s;
    } else if (bid < 18) {  // Ws~ [32][16][8]
        const int i = (bid - 2) * 256 + tid;
        int j = i % 8, c = (i / 8) % 16, o = i / 128;
        float s = 0.0f;
#pragma unroll
        for (int q = 0; q < 4; ++q) s += ws4[(o * 64 + c * 4 + q) * 8 + j];
        wr[512 + i] = s;
    } else {  // pwB packing: 768 + 3072 + 6144 = 9984 u32 items
        int g = (bid - 18) * 256 + tid;
        if (g < 9984) {
            const float *wb, *ws;
            unsigned* dst;
            int NT, O, rel;
            if (g < 768) {
                wb = wb1; ws = ws1; NT = 9; O = 4; rel = g;
                dst = (unsigned*)(wsbase + 4640);
            } else if (g < 3840) {
                wb = wb2; ws = ws2; NT = 36; O = 8; rel = g - 768;
                dst = (unsigned*)(wsbase + 5408);
            } else {
                wb = wb3; ws = ws3; NT = 72; O = 16; rel = g - 3840;
                dst = (unsigned*)(wsbase + 8480);
            }
            int kf = rel >> 8;
            int lane = (rel >> 2) & 63;
            int j = rel & 3;
            int k0 = kf * 32 + ((lane >> 4) & 3) * 8 + j * 2;
            int n = lane & 15;
            dst[rel] = packw(wval(wb, ws, NT, O, n, k0),
                             wval(wb, ws, NT, O, n, k0 + 1));
        }
    }
}

// ---------------------------------------------------------------------------
// Fused network, one block (4 waves) per sample. Phase-split planes:
// 2 x 8 KB (+64B skew) = 16448 B; total LDS ~19.6 KB. launch_bounds(256,7):
// 7 blocks/CU (28 waves, 87.5%) with VGPR cap 73 -> no spill (round-14's
// (256,8) capped at 32+spill; round-13's unconstrained build used 64).
// ---------------------------------------------------------------------------
__global__ __launch_bounds__(256, 7) void kan_fused(
    const float* __restrict__ x, const float* __restrict__ wsbase,
    const float* __restrict__ fcw, const float* __restrict__ fcb,
    float* __restrict__ out) {
    __shared__ uint4 s_planes4[1028];  // 16448 B (bases + skew + sil)
    __shared__ float s_next[784];
    char* planes = (char*)s_planes4;

    const int b = blockIdx.x;
    const int tid = threadIdx.x;
    const float* wr = wsbase;
    const uint4* pw1 = (const uint4*)(wsbase + 4640);
    const uint4* pw2 = (const uint4*)(wsbase + 5408);
    const uint4* pw3 = (const uint4*)(wsbase + 8480);

    // ----- layer 1: [1,28,28] -> [4,14,14], two spatial phases
#pragma unroll 1
    for (int p = 0; p < 2; ++p) {
        expand_win<1, 28, 28, 16>(x + (size_t)b * 784, p * 14, planes, tid);
        __syncthreads();
        conv_pool_l1<28, 28, 4, 3, 4, 7, 14, 14, 16>(pw1, planes, s_next, tid,
                                                     p * 7);
        __syncthreads();
    }

    // ----- layer 2: [4,14,14] -> [8,7,7], two cin phases (acc persists)
    {
        f32x4 acc[4];
#pragma unroll
        for (int i = 0; i < 4; ++i) acc[i] = {0.f, 0.f, 0.f, 0.f};
#pragma unroll 1
        for (int p = 0; p < 2; ++p) {
            expand_win<2, 14, 14, 16>(s_next + p * 392, 0, planes, tid);
            __syncthreads();
            conv_accum<14, 14, 6, 3, 2, 4, 16>(pw2 + p * 6 * 64, planes, tid, acc);
            __syncthreads();
        }
        pool_tiles<8, 2, 4, 7, 7>(acc, tid, s_next);
        __syncthreads();
    }

    // ----- layer 3: [8,7,7] -> [16,3,3], two cin phases (acc persists)
    {
        f32x4 acc1 = {0.f, 0.f, 0.f, 0.f};
#pragma unroll 1
        for (int p = 0; p < 2; ++p) {
            expand_win<4, 7, 7, 9>(s_next + p * 196, 0, planes, tid);
            __syncthreads();
            conv_accum<7, 7, 12, 4, 1, 1, 9>(pw3 + p * 12 * 64, planes, tid,
                                             &acc1);
            __syncthreads();
        }
        pool_tiles<16, 1, 1, 3, 3>(&acc1, tid, s_next);
        __syncthreads();
    }

    // ----- layer 4 + global-avg + fc (collapsed via wr), s_next = [16][3][3]
    float* s_exp = (float*)s_planes4;          // 1296 floats @ bytes [0, 5184)
    float* s_sum = (float*)s_planes4 + 1344;   // 144 floats @ bytes [5376, 5952)
    float* s_pool = (float*)s_planes4 + 1504;  // 32 floats @ bytes [6016, 6144)
    if (tid < 144) {
        float v = s_next[tid];
        float bb[8];
        bspline8(v, bb);
        s_exp[tid * 9 + 0] = silu_f(v);
#pragma unroll
        for (int j = 0; j < 8; ++j) s_exp[tid * 9 + 1 + j] = bb[j];
    }
    __syncthreads();
    if (tid < 144) {
        int c = tid / 9, comp = tid - (tid / 9) * 9;
        float s = 0.0f;
#pragma unroll
        for (int p = 0; p < 9; ++p) s += s_exp[(c * 9 + p) * 9 + comp];
        s_sum[tid] = s;
    }
    __syncthreads();
    if (tid < 32) {
        int o = tid;
        float acc = wr[4608 + o];
        for (int c = 0; c < 16; ++c) {
            acc += wr[o * 16 + c] * s_sum[c * 9 + 0];
#pragma unroll
            for (int j = 0; j < 8; ++j)
                acc += wr[512 + (o * 16 + c) * 8 + j] * s_sum[c * 9 + 1 + j];
        }
        s_pool[o] = acc * (1.0f / 16.0f);
    }
    __syncthreads();
    if (tid < 10) {
        float acc = fcb[tid];
#pragma unroll
        for (int c = 0; c < 32; ++c) acc += fcw[tid * 32 + c] * s_pool[c];
        out[(size_t)b * 10 + tid] = acc;
    }
}

// ---------------------------------------------------------------------------
extern "C" void kernel_launch(void* const* d_in, const int* in_sizes, int n_in,
                              void* d_out, int out_size, void* d_ws, size_t ws_size,
                              hipStream_t stream) {
    const float* x = (const float*)d_in[0];      // [B,1,28,28]
    const float* wb1 = (const float*)d_in[1];    // [4,9]
    const float* ws1 = (const float*)d_in[2];    // [4,9,8]
    const float* wb2 = (const float*)d_in[3];    // [8,36]
    const float* ws2 = (const float*)d_in[4];    // [8,36,8]
    const float* wb3 = (const float*)d_in[5];    // [16,72]
    const float* ws3 = (const float*)d_in[6];    // [16,72,8]
    const float* wb4 = (const float*)d_in[7];    // [32,64]
    const float* ws4 = (const float*)d_in[8];    // [32,64,8]
    const float* fcw = (const float*)d_in[9];    // [10,32]
    const float* fcb = (const float*)d_in[10];   // [10]
    float* out = (float*)d_out;

    const int B = in_sizes[0] / (28 * 28);
    float* wsbase = (float*)d_ws;  // 14624 floats used

    kan_prep<<<57, 256, 0, stream>>>(wb1, ws1, wb2, ws2, wb3, ws3, wb4, ws4,
                                     wsbase);
    kan_fused<<<B, 256, 0, stream>>>(x, wsbase, fcw, fcb, out);
}

// Round 16
// 47.440 us; speedup vs baseline: 1.1109x; 1.1109x over previous
//
#include <hip/hip_runtime.h>

#define DEV __device__ __forceinline__

typedef __fp16 h8 __attribute__((ext_vector_type(8)));
typedef __fp16 f2 __attribute__((ext_vector_type(2)));
typedef float f32x4 __attribute__((ext_vector_type(4)));
union U4H { uint4 u; h8 h; };
union HS { _Float16 h; unsigned short s; };

DEV unsigned h16(float x) { HS z; z.h = (_Float16)x; return (unsigned)z.s; }
DEV unsigned f2bits(f2 h) { union { f2 h; unsigned u; } x; x.h = h; return x.u; }
DEV float silu_f(float v) { return v / (1.0f + __expf(-v)); }

// bases plane: B0..B7 per cell (16B) at 0; sil plane at SIL_OFF (+64B skew:
// 8256/4 % 32 = 16 -> lane-half 3 decorrelated from halves 0-2).
// Plane capacity 512 cells (8 KB) each; layers are phase-split to fit.
#define SIL_OFF 8256

// Cox-de Boor (reference-exact) — used only in prep/tail (cheap paths).
DEV void bspline8(float x, float bb[8]) {
    float b[11];
#pragma unroll
    for (int i = 0; i < 11; ++i) {
        float g0 = (i - 3) * 0.4f - 1.0f;
        float g1 = (i - 2) * 0.4f - 1.0f;
        b[i] = ((x >= g0) && (x < g1)) ? 1.0f : 0.0f;
    }
#pragma unroll
    for (int d = 1; d <= 3; ++d) {
        const float inv = 1.0f / (0.4f * (float)d);
#pragma unroll
        for (int i = 0; i < 11 - d; ++i) {
            float gl = (i - 3) * 0.4f - 1.0f;
            float gr = (i - 3 + d + 1) * 0.4f - 1.0f;
            b[i] = (x - gl) * inv * b[i] + (gr - x) * inv * b[i + 1];
        }
    }
#pragma unroll
    for (int j = 0; j < 8; ++j) bb[j] = b[j];
}

DEV unsigned silpair(float sil) {
    unsigned sh = h16(sil);
    float shf = (float)(_Float16)sil;
    unsigned slo = h16(sil - shf);
    return sh | (slo << 16);
}

// ---------------------------------------------------------------------------
// Windowed expansion: CINP channels x NROWS cell-rows into the plane pair.
// Cell row r maps to image row y = row0 + r - 1 (border cells -> x=0 exp).
// Two conflict-free ds_write_b128 per cell; row-sil via __shfl_down sharing
// (mismatch only at cols WC-2/WC-1, never read since px <= W-1).
// ---------------------------------------------------------------------------
template <int CINP, int H, int W, int NROWS>
DEV void expand_win(const float* src, int row0, char* planes, int tid) {
    constexpr int WC = W + 2;
    constexpr int CELLS = CINP * NROWS * WC;
    const int ln = tid & 63;
    for (int cell = tid; cell < CELLS; cell += 256) {
        int c = cell / (NROWS * WC);
        int rr = cell - c * (NROWS * WC);
        int r = rr / WC, col = rr - r * WC;
        int y = row0 + r - 1, x = col - 1;
        bool yin = (unsigned)y < (unsigned)H;
        const float* srow = src + c * H * W + y * W;

        float v0 = (yin && (unsigned)x < (unsigned)W) ? srow[x] : 0.0f;

        // bases of THIS cell (closed-form cardinal cubic, funnel-shift place)
        float u = (v0 + 2.2f) * 2.5f;
        int mi = (int)u;
        bool valid = (u >= 0.0f) && (u < 11.0f);
        float t = u - (float)mi;
        float t2 = t * t, t3 = t2 * t;
        float omt = 1.0f - t;
        float p3 = omt * omt * omt * (1.0f / 6.0f);
        float p2 = (3.0f * t3 - 6.0f * t2 + 4.0f) * (1.0f / 6.0f);
        float p1 = (-3.0f * t3 + 3.0f * t2 + 3.0f * t + 1.0f) * (1.0f / 6.0f);
        float p0 = t3 * (1.0f / 6.0f);
        unsigned d0 = f2bits(__builtin_amdgcn_cvt_pkrtz(p3, p2));
        unsigned d1 = f2bits(__builtin_amdgcn_cvt_pkrtz(p1, p0));
        unsigned long long P = ((unsigned long long)d1 << 32) | d0;
        unsigned long long lo64 = 0ull, hi64 = 0ull;
        int shamt = (mi - 3) * 16;
        if (valid) {
            if (shamt < 0) {
                lo64 = P >> (-shamt);
            } else if (shamt < 64) {
                lo64 = P << shamt;
                hi64 = shamt ? (P >> (64 - shamt)) : 0ull;
            } else {
                hi64 = P << (shamt - 64);
            }
        }
        uint4 brec;
        brec.x = (unsigned)lo64;
        brec.y = (unsigned)(lo64 >> 32);
        brec.z = (unsigned)hi64;
        brec.w = (unsigned)(hi64 >> 32);
        *(uint4*)(planes + (size_t)cell * 16) = brec;  // store early: lower live range

        unsigned sp0 = silpair(silu_f(v0));
        unsigned sp1 = __shfl_down(sp0, 1);
        unsigned sp2 = __shfl_down(sp0, 2);
        if (ln >= 62) {
            float v1 = (yin && (unsigned)(x + 1) < (unsigned)W) ? srow[x + 1] : 0.0f;
            float v2 = (yin && (unsigned)(x + 2) < (unsigned)W) ? srow[x + 2] : 0.0f;
            sp1 = silpair(silu_f(v1));
            sp2 = silpair(silu_f(v2));
        }
        uint4 srec;
        srec.x = sp0;
        srec.y = sp1;
        srec.z = sp2;
        srec.w = 0u;
        *(uint4*)(planes + SIL_OFF + (size_t)cell * 16) = srec;
    }
}

// chunk rc = (local cin, dy): base cell offset (dx=0) in the planes.
template <int NROWS, int SC>
DEV constexpr int chunkcell(int rc) {
    return ((rc / 3) * NROWS + (rc % 3)) * SC;
}

// 2x2/2 maxpool of a 16x16 C-tile (rows = 2x8 positions, cols = channels)
template <int O, int PHV, int PWV>
DEV void poolwrite(f32x4 acc, int ty, int tx, int ln, float* s_next) {
    const int n = ln & 15, q = ln >> 4;
    float q0 = fmaxf(acc[0], acc[1]);
    float q1 = fmaxf(acc[2], acc[3]);
    float r0 = fmaxf(q0, __shfl_xor(q0, 32));
    float r1 = fmaxf(q1, __shfl_xor(q1, 32));
    if (ln < 32 && n < O && ty < PHV) {
        int ppx = tx * 4 + (q & 1) * 2;
        float* dst = s_next + n * (PHV * PWV) + ty * PWV + ppx;
        if (ppx < PWV) dst[0] = r0;
        if (ppx + 1 < PWV) dst[1] = r1;
    }
}

// ---------------------------------------------------------------------------
// L1 spatial-phase conv+pool: tiles for pool rows [ty_off, ty_off+TPW*4/TX),
// plane holds local rows 0..NROWS-1. Single B-set (KC chunks resident).
// ---------------------------------------------------------------------------
template <int H, int W, int O, int KC, int TX, int TPW, int PHV, int PWV,
          int NROWS>
DEV void conv_pool_l1(const uint4* __restrict__ pwB, const char* planes,
                      float* s_next, int tid, int ty_off) {
    constexpr int SC = W + 2;
    const int wv = tid >> 6, ln = tid & 63;
    const int m = ln & 15;
    const int half = ln >> 4;
    const int lane_off = (half == 3) ? SIL_OFF : half * 16;

    uint4 bw[KC];
#pragma unroll
    for (int i = 0; i < KC; ++i) bw[i] = pwB[i * 64 + ln];
#pragma unroll
    for (int tt = 0; tt < TPW; ++tt) {
        const int gid = wv * TPW + tt;
        const int tyl = gid / TX, tx = gid - tyl * TX;
        const int py = 2 * tyl + (m >> 3);  // local row, <= NROWS-3
        const int px = min(tx * 8 + (m & 7), W - 1);
        const int base = (py * SC + px) * 16 + lane_off;
        f32x4 acc = {0.f, 0.f, 0.f, 0.f};
#pragma unroll
        for (int i = 0; i < KC; ++i) {
            const int off = chunkcell<NROWS, SC>(i) * 16;
            U4H a; a.u = *(const uint4*)(planes + base + off);
            U4H b; b.u = bw[i];
            acc = __builtin_amdgcn_mfma_f32_16x16x32_f16(a.h, b.h, acc, 0, 0, 0);
        }
        poolwrite<O, PHV, PWV>(acc, ty_off + tyl, tx, ln, s_next);
    }
}

// ---------------------------------------------------------------------------
// Channel-phase accumulate-only conv: KCP chunks of this phase into acc[TPW].
// BWC kept small (3-4) to bound resident bw[] register pressure (the accum
// loops are where acc + bw + base are simultaneously live -> spill source).
// ---------------------------------------------------------------------------
template <int H, int W, int KCP, int BWC, int TX, int TPW, int NROWS>
DEV void conv_accum(const uint4* __restrict__ pwB, const char* planes, int tid,
                    f32x4* acc) {
    constexpr int SC = W + 2;
    const int wv = tid >> 6, ln = tid & 63;
    const int m = ln & 15;
    const int half = ln >> 4;
    const int lane_off = (half == 3) ? SIL_OFF : half * 16;

    int base[TPW];
#pragma unroll
    for (int tt = 0; tt < TPW; ++tt) {
        const int gid = wv * TPW + tt;
        const int ty = gid / TX, tx = gid - ty * TX;
        const int py = min(2 * ty + (m >> 3), H - 1);
        const int px = min(tx * 8 + (m & 7), W - 1);
        base[tt] = (py * SC + px) * 16 + lane_off;
    }
#pragma unroll
    for (int kc = 0; kc < KCP; kc += BWC) {
        uint4 bw[BWC];
#pragma unroll
        for (int i = 0; i < BWC; ++i) bw[i] = pwB[(kc + i) * 64 + ln];
#pragma unroll
        for (int i = 0; i < BWC; ++i) {
            const int off = chunkcell<NROWS, SC>(kc + i) * 16;
#pragma unroll
            for (int tt = 0; tt < TPW; ++tt) {
                U4H a; a.u = *(const uint4*)(planes + base[tt] + off);
                U4H b; b.u = bw[i];
                acc[tt] = __builtin_amdgcn_mfma_f32_16x16x32_f16(a.h, b.h, acc[tt], 0, 0, 0);
            }
        }
    }
}

template <int O, int TX, int TPW, int PHV, int PWV>
DEV void pool_tiles(const f32x4* acc, int tid, float* s_next) {
    const int wv = tid >> 6, ln = tid & 63;
#pragma unroll
    for (int tt = 0; tt < TPW; ++tt) {
        const int gid = wv * TPW + tt;
        const int ty = gid / TX, tx = gid - ty * TX;
        poolwrite<O, PHV, PWV>(acc[tt], ty, tx, ln, s_next);
    }
}

// ---------------------------------------------------------------------------
// Prep: wr (collapsed layer-4 weights) + fragment-packed B for layers 1..3.
// K slot s within chunk (cin,dy): s<24 -> ws[tap(cin,dy,s/8), s%8];
// s in 24..29 -> f16(wb[tap(cin,dy,(s-24)/2)]); s=30,31 -> 0.
// d_ws f32 offsets: wr[0,4640); pwB1@4640 (768 u32); pwB2@5408 (3072);
// pwB3@8480 (6144).
// ---------------------------------------------------------------------------
DEV float wval(const float* wb, const float* ws, int NT, int O, int n, int k) {
    int chunk = k >> 5, s = k & 31;
    int cin = chunk / 3, dy = chunk - 3 * (chunk / 3);
    if (n >= O) return 0.f;
    if (s < 24) {
        int dx = s >> 3, j = s & 7;
        return ws[(n * NT + cin * 9 + dy * 3 + dx) * 8 + j];
    }
    if (s < 30) {
        int dx = (s - 24) >> 1;
        return (float)(_Float16)wb[n * NT + cin * 9 + dy * 3 + dx];
    }
    return 0.f;
}

DEV unsigned packw(float a, float b) { return h16(a) | (h16(b) << 16); }

__global__ __launch_bounds__(256) void kan_prep(
    const float* __restrict__ wb1, const float* __restrict__ ws1,
    const float* __restrict__ wb2, const float* __restrict__ ws2,
    const float* __restrict__ wb3, const float* __restrict__ ws3,
    const float* __restrict__ wb4, const float* __restrict__ ws4,
    float* __restrict__ wsbase) {
    float* wr = wsbase;
    const int bid = blockIdx.x;
    const int tid = threadIdx.x;

    if (bid == 0) {  // Wb~ [32][16]
        for (int i = tid; i < 512; i += 256) {
            int o = i / 16, c = i % 16;
            float s = 0.0f;
#pragma unroll
            for (int q = 0; q < 4; ++q) s += wb4[o * 64 + c * 4 + q];
            wr[i] = s;
        }
    } else if (bid == 1) {  // beta7[o] = 7 * sum_{f,j} ws4[o,f,j] * B_j(0)
        __shared__ float zb[8];
        if (tid == 0) {
            float zbb[8];
            bspline8(0.0f, zbb);
#pragma unroll
            for (int j = 0; j < 8; ++j) zb[j] = zbb[j];
        }
        __syncthreads();
        const int o = tid >> 3, j = tid & 7;
        float s = 0.0f;
        for (int f = 0; f < 64; ++f) s += ws4[(o * 64 + f) * 8 + j];
        s *= zb[j];
        s += __shfl_xor(s, 1);
        s += __shfl_xor(s, 2);
        s += __shfl_xor(s, 4);
        if (j == 0) wr[4608 + o] = 7.0f * s;
    } else if (bid < 18) {  // Ws~ [32][16][8]
        const int i = (bid - 2) * 256 + tid;
        int j = i % 8, c = (i / 8) % 16, o = i / 128;
        float s = 0.0f;
#pragma unroll
        for (int q = 0; q < 4; ++q) s += ws4[(o * 64 + c * 4 + q) * 8 + j];
        wr[512 + i] = s;
    } else {  // pwB packing: 768 + 3072 + 6144 = 9984 u32 items
        int g = (bid - 18) * 256 + tid;
        if (g < 9984) {
            const float *wb, *ws;
            unsigned* dst;
            int NT, O, rel;
            if (g < 768) {
                wb = wb1; ws = ws1; NT = 9; O = 4; rel = g;
                dst = (unsigned*)(wsbase + 4640);
            } else if (g < 3840) {
                wb = wb2; ws = ws2; NT = 36; O = 8; rel = g - 768;
                dst = (unsigned*)(wsbase + 5408);
            } else {
                wb = wb3; ws = ws3; NT = 72; O = 16; rel = g - 3840;
                dst = (unsigned*)(wsbase + 8480);
            }
            int kf = rel >> 8;
            int lane = (rel >> 2) & 63;
            int j = rel & 3;
            int k0 = kf * 32 + ((lane >> 4) & 3) * 8 + j * 2;
            int n = lane & 15;
            dst[rel] = packw(wval(wb, ws, NT, O, n, k0),
                             wval(wb, ws, NT, O, n, k0 + 1));
        }
    }
}

// ---------------------------------------------------------------------------
// Fused network, one block (4 waves) per sample. Phase-split planes:
// 2 x 8 KB (+64B skew) = 16448 B; total LDS ~19.6 KB -> 8 blocks/CU with
// launch_bounds(256,8) (round-14 best config) + small BWC (round-15's
// register-pressure reduction).
// ---------------------------------------------------------------------------
__global__ __launch_bounds__(256, 8) void kan_fused(
    const float* __restrict__ x, const float* __restrict__ wsbase,
    const float* __restrict__ fcw, const float* __restrict__ fcb,
    float* __restrict__ out) {
    __shared__ uint4 s_planes4[1028];  // 16448 B (bases + skew + sil)
    __shared__ float s_next[784];
    char* planes = (char*)s_planes4;

    const int b = blockIdx.x;
    const int tid = threadIdx.x;
    const float* wr = wsbase;
    const uint4* pw1 = (const uint4*)(wsbase + 4640);
    const uint4* pw2 = (const uint4*)(wsbase + 5408);
    const uint4* pw3 = (const uint4*)(wsbase + 8480);

    // ----- layer 1: [1,28,28] -> [4,14,14], two spatial phases
#pragma unroll 1
    for (int p = 0; p < 2; ++p) {
        expand_win<1, 28, 28, 16>(x + (size_t)b * 784, p * 14, planes, tid);
        __syncthreads();
        conv_pool_l1<28, 28, 4, 3, 4, 7, 14, 14, 16>(pw1, planes, s_next, tid,
                                                     p * 7);
        __syncthreads();
    }

    // ----- layer 2: [4,14,14] -> [8,7,7], two cin phases (acc persists)
    {
        f32x4 acc[4];
#pragma unroll
        for (int i = 0; i < 4; ++i) acc[i] = {0.f, 0.f, 0.f, 0.f};
#pragma unroll 1
        for (int p = 0; p < 2; ++p) {
            expand_win<2, 14, 14, 16>(s_next + p * 392, 0, planes, tid);
            __syncthreads();
            conv_accum<14, 14, 6, 3, 2, 4, 16>(pw2 + p * 6 * 64, planes, tid, acc);
            __syncthreads();
        }
        pool_tiles<8, 2, 4, 7, 7>(acc, tid, s_next);
        __syncthreads();
    }

    // ----- layer 3: [8,7,7] -> [16,3,3], two cin phases (acc persists)
    {
        f32x4 acc1 = {0.f, 0.f, 0.f, 0.f};
#pragma unroll 1
        for (int p = 0; p < 2; ++p) {
            expand_win<4, 7, 7, 9>(s_next + p * 196, 0, planes, tid);
            __syncthreads();
            conv_accum<7, 7, 12, 4, 1, 1, 9>(pw3 + p * 12 * 64, planes, tid,
                                             &acc1);
            __syncthreads();
        }
        pool_tiles<16, 1, 1, 3, 3>(&acc1, tid, s_next);
        __syncthreads();
    }

    // ----- layer 4 + global-avg + fc (collapsed via wr), s_next = [16][3][3]
    float* s_exp = (float*)s_planes4;          // 1296 floats @ bytes [0, 5184)
    float* s_sum = (float*)s_planes4 + 1344;   // 144 floats @ bytes [5376, 5952)
    float* s_pool = (float*)s_planes4 + 1504;  // 32 floats @ bytes [6016, 6144)
    if (tid < 144) {
        float v = s_next[tid];
        float bb[8];
        bspline8(v, bb);
        s_exp[tid * 9 + 0] = silu_f(v);
#pragma unroll
        for (int j = 0; j < 8; ++j) s_exp[tid * 9 + 1 + j] = bb[j];
    }
    __syncthreads();
    if (tid < 144) {
        int c = tid / 9, comp = tid - (tid / 9) * 9;
        float s = 0.0f;
#pragma unroll
        for (int p = 0; p < 9; ++p) s += s_exp[(c * 9 + p) * 9 + comp];
        s_sum[tid] = s;
    }
    __syncthreads();
    if (tid < 32) {
        int o = tid;
        float acc = wr[4608 + o];
        for (int c = 0; c < 16; ++c) {
            acc += wr[o * 16 + c] * s_sum[c * 9 + 0];
#pragma unroll
            for (int j = 0; j < 8; ++j)
                acc += wr[512 + (o * 16 + c) * 8 + j] * s_sum[c * 9 + 1 + j];
        }
        s_pool[o] = acc * (1.0f / 16.0f);
    }
    __syncthreads();
    if (tid < 10) {
        float acc = fcb[tid];
#pragma unroll
        for (int c = 0; c < 32; ++c) acc += fcw[tid * 32 + c] * s_pool[c];
        out[(size_t)b * 10 + tid] = acc;
    }
}

// ---------------------------------------------------------------------------
extern "C" void kernel_launch(void* const* d_in, const int* in_sizes, int n_in,
                              void* d_out, int out_size, void* d_ws, size_t ws_size,
                              hipStream_t stream) {
    const float* x = (const float*)d_in[0];      // [B,1,28,28]
    const float* wb1 = (const float*)d_in[1];    // [4,9]
    const float* ws1 = (const float*)d_in[2];    // [4,9,8]
    const float* wb2 = (const float*)d_in[3];    // [8,36]
    const float* ws2 = (const float*)d_in[4];    // [8,36,8]
    const float* wb3 = (const float*)d_in[5];    // [16,72]
    const float* ws3 = (const float*)d_in[6];    // [16,72,8]
    const float* wb4 = (const float*)d_in[7];    // [32,64]
    const float* ws4 = (const float*)d_in[8];    // [32,64,8]
    const float* fcw = (const float*)d_in[9];    // [10,32]
    const float* fcb = (const float*)d_in[10];   // [10]
    float* out = (float*)d_out;

    const int B = in_sizes[0] / (28 * 28);
    float* wsbase = (float*)d_ws;  // 14624 floats used

    kan_prep<<<57, 256, 0, stream>>>(wb1, ws1, wb2, ws2, wb3, ws3, wb4, ws4,
                                     wsbase);
    kan_fused<<<B, 256, 0, stream>>>(x, wsbase, fcw, fcb, out);
}